// Round 5
// baseline (329.531 us; speedup 1.0000x reference)
//
#include <hip/hip_runtime.h>

// Problem constants (reference: H = W = 2048, C = 8, N = 1e6)
#define HH 2048
#define WW 2048
#define CC 8
#define MODV 2044.0f     // H - 4
#define NB 128           // row bands: 2044 rows / 16 per band
#define BAND_SHIFT 4     // 16 rows per band -> ~1.1 MB working set per band

typedef float f32x2 __attribute__((ext_vector_type(2)));
typedef float f32x4 __attribute__((ext_vector_type(4)));

__device__ __forceinline__ f32x4 blerp4(f32x4 tl, f32x4 tr, f32x4 bl, f32x4 br,
                                        float d0, float d1, float m) {
    f32x4 mb = br + d0 * (bl - br);
    f32x4 mt = tr + d0 * (tl - tr);
    return m + 0.0f, mb + d1 * (mt - mb);  // (comma-expr avoided below; see note)
}

// NOTE: the line above must not exist in production code; real body follows.
// (Rewritten cleanly:)
__device__ __forceinline__ f32x4 blerp4_clean(f32x4 tl, f32x4 tr, f32x4 bl, f32x4 br,
                                              float d0, float d1, float m) {
    f32x4 mb = br + d0 * (bl - br);
    f32x4 mt = tr + d0 * (tl - tr);
    return m * (mb + d1 * (mt - mb));
}
#define blerp4 blerp4_clean

// cx, cy are the post-mod coords: cx = (x-1) mod 2044 + 1, in [1, 2045)
__device__ __forceinline__ void mod_coords(f32x2 co, float& cx, float& cy) {
    float x = co.x - 1.0f;
    float y = co.y - 1.0f;
    cx = fmodf(x, MODV); if (cx < 0.0f) cx += MODV; cx += 1.0f;
    cy = fmodf(y, MODV); if (cy < 0.0f) cy += MODV; cy += 1.0f;
}

// Full bilinear interp + store for one point (reference naming preserved:
// tl=V[i0][i1], tr=V[i0+1][i1], bl=V[i0][i1+1], br=V[i0+1][i1+1]).
__device__ __forceinline__ void interp_store(const float* __restrict__ visible,
                                             float* __restrict__ out,
                                             float cx, float cy, unsigned oi) {
    float fx = floorf(cx);
    float fy = floorf(cy);
    float d0 = cx - fx;          // delta along dim 0 (rows)
    float d1 = cy - fy;          // delta along dim 1 (cols)
    int i0 = (int)fx;            // row in [1, 2044]
    int i1 = (int)fy;            // col in [1, 2044]
    float m = (cx > (float)HH) ? 0.0f : 1.0f;   // unreachable, kept for fidelity

    const float* p = visible + ((size_t)i0 * WW + (size_t)i1) * CC;
    const size_t RS = (size_t)WW * CC;
    f32x4 tl0 = *(const f32x4*)(p);
    f32x4 tl1 = *(const f32x4*)(p + 4);
    f32x4 bl0 = *(const f32x4*)(p + 8);        // col+1, contiguous
    f32x4 bl1 = *(const f32x4*)(p + 12);
    f32x4 tr0 = *(const f32x4*)(p + RS);       // row+1
    f32x4 tr1 = *(const f32x4*)(p + RS + 4);
    f32x4 br0 = *(const f32x4*)(p + RS + 8);
    f32x4 br1 = *(const f32x4*)(p + RS + 12);

    f32x4 o0 = blerp4(tl0, tr0, bl0, br0, d0, d1, m);
    f32x4 o1 = blerp4(tl1, tr1, bl1, br1, d0, d1, m);
    float* po = out + (size_t)oi * CC;
    *(f32x4*)po = o0;
    *(f32x4*)(po + 4) = o1;
}

// ---------------- pass 0: zero bin cursors ----------------
__global__ void zero_cnt(unsigned* __restrict__ cnt) {
    cnt[threadIdx.x] = 0u;
}

// ---------------- pass 1: bin points by row-band ----------------
// key layout is XCD-major: key = (band%8)*16 + band/8, so XCD x's 16 bands
// occupy slots [x*16*cap, (x+1)*16*cap) contiguously.
__global__ __launch_bounds__(256) void bin_points(
    const float* __restrict__ coords,
    const float* __restrict__ visible,   // only for overflow fallback
    float* __restrict__ out,             // only for overflow fallback
    unsigned* __restrict__ cnt,
    float* __restrict__ rcx, float* __restrict__ rcy,
    unsigned* __restrict__ ridx,
    int n, int cap)
{
    __shared__ unsigned lcnt[NB];
    __shared__ unsigned lbase[NB];
    int tid = threadIdx.x;
    if (tid < NB) lcnt[tid] = 0u;
    __syncthreads();

    int i = blockIdx.x * 256 + tid;
    bool valid = i < n;
    float cx = 1.0f, cy = 1.0f;
    int key = 0;
    unsigned lr = 0;
    if (valid) {
        f32x2 co = reinterpret_cast<const f32x2*>(coords)[i];
        mod_coords(co, cx, cy);
        int i0 = (int)floorf(cx);                 // [1, 2044]
        int band = (i0 - 1) >> BAND_SHIFT;        // [0, 127]
        key = ((band & 7) << 4) | (band >> 3);    // XCD-major
        lr = atomicAdd(&lcnt[key], 1u);           // local rank within block
    }
    __syncthreads();
    if (tid < NB && lcnt[tid]) lbase[tid] = atomicAdd(&cnt[tid], lcnt[tid]);
    __syncthreads();
    if (valid) {
        unsigned p = lbase[key] + lr;
        if (p < (unsigned)cap) {
            int slot = key * cap + (int)p;
            rcx[slot] = cx;
            rcy[slot] = cy;
            ridx[slot] = (unsigned)i;
        } else {
            // bin overflow (~4σ event at cap=8192; handful of points at most):
            // stay correct, compute this point directly.
            interp_store(visible, out, cx, cy, (unsigned)i);
        }
    }
}

// ---------------- pass 2: lean gather, 1 point/thread ----------------
// cap is a power of two; each 256-slot chunk lies in exactly one bin, so
// bin/rank come from shifts on blockIdx only (uniform -> cnt[bin] is an
// s_load; no division, no loop, single wait chain: records -> gathers).
// blockIdx%8 selects the XCD territory (locality heuristic only).
__global__ __launch_bounds__(256) void gather_binned2(
    const float* __restrict__ visible,
    float* __restrict__ out,
    const unsigned* __restrict__ cnt,
    const float* __restrict__ rcx, const float* __restrict__ rcy,
    const unsigned* __restrict__ ridx,
    int cap_mask,        // cap - 1
    int cpb_shift)       // log2(cap / 256)
{
    int per_xcd = gridDim.x >> 3;            // chunks per XCD territory
    int xcd = blockIdx.x & 7;
    int j   = blockIdx.x >> 3;
    int c   = xcd * per_xcd + j;             // global chunk id, territory-major
    int bin = c >> cpb_shift;                // uniform
    unsigned cb = cnt[bin];                  // uniform scalar load
    unsigned capu = (unsigned)cap_mask + 1u;
    if (cb > capu) cb = capu;

    int slot = c * 256 + threadIdx.x;
    unsigned r = (unsigned)(slot & cap_mask);
    if (r < cb) {
        float cx = rcx[slot];
        float cy = rcy[slot];
        unsigned oi = ridx[slot];
        interp_store(visible, out, cx, cy, oi);
    }
}

// ---------------- fallback: direct (no workspace) ----------------
__global__ __launch_bounds__(256) void idx2pixel_direct(
    const float* __restrict__ coords,
    const float* __restrict__ visible,
    float* __restrict__ out, int n)
{
    int t = blockIdx.x * blockDim.x + threadIdx.x;
    if (t >= n) return;
    f32x2 co = reinterpret_cast<const f32x2*>(coords)[t];
    float cx, cy;
    mod_coords(co, cx, cy);
    interp_store(visible, out, cx, cy, (unsigned)t);
}

extern "C" void kernel_launch(void* const* d_in, const int* in_sizes, int n_in,
                              void* d_out, int out_size, void* d_ws, size_t ws_size,
                              hipStream_t stream) {
    const float* coords  = (const float*)d_in[0];  // (N, 2) fp32
    const float* visible = (const float*)d_in[1];  // (2048, 2048, 8) fp32
    float* out = (float*)d_out;                    // (N, 8) fp32
    int n = in_sizes[0] / 2;

    // cap: next power of two >= mean bin load, with ~4% minimum headroom
    // (n=1e6 -> mean 7813 -> cap 8192, +4.3 sigma; overflow is handled).
    int mean = (n + NB - 1) / NB;
    int cap = 256;
    while (cap < mean) cap <<= 1;
    if (cap - mean < mean / 24) cap <<= 1;

    size_t slots = (size_t)NB * (size_t)cap;
    size_t need = 1024 + slots * 12;               // cnt pad + cx,cy,idx SoA

    if (ws_size >= need && n >= (1 << 17)) {
        unsigned* cnt = (unsigned*)d_ws;
        float* rcx = (float*)((char*)d_ws + 1024);
        float* rcy = rcx + slots;
        unsigned* ridx = (unsigned*)(rcy + slots);

        int cpb = cap / 256;                       // chunks per bin (pow2)
        int cpb_shift = __builtin_ctz(cpb);
        int total_chunks = NB * cpb;               // divisible by 8

        zero_cnt<<<1, NB, 0, stream>>>(cnt);
        int nb1 = (n + 255) / 256;
        bin_points<<<nb1, 256, 0, stream>>>(coords, visible, out, cnt,
                                            rcx, rcy, ridx, n, cap);
        gather_binned2<<<total_chunks, 256, 0, stream>>>(visible, out, cnt,
                                                         rcx, rcy, ridx,
                                                         cap - 1, cpb_shift);
    } else {
        int block = 256;
        int grid = (n + block - 1) / block;
        idx2pixel_direct<<<grid, block, 0, stream>>>(coords, visible, out, n);
    }
}

// Round 7
// 216.245 us; speedup vs baseline: 1.5239x; 1.5239x over previous
//
#include <hip/hip_runtime.h>

// Problem constants (reference: H = W = 2048, C = 8, N = 1e6)
#define HH 2048
#define WW 2048
#define CC 8
#define MODV 2044.0f   // H - 4

typedef float f32x2 __attribute__((ext_vector_type(2)));
typedef float f32x4 __attribute__((ext_vector_type(4)));

// Cooperative gather: 4 lanes per point.
//
// Measured invariant (R0-R5): dur ~= (line-transactions) x ~5.9 cyc/CU,
// independent of residency (L2 vs HBM), MLP, occupancy. Divergent 16B lane
// accesses cost one 64B-line transaction each; same-line lanes within ONE
// instruction merge (fill kernel: 5.9 cyc/line, 4 lanes/line).
//
// Memory layout per point: row i0 holds [tl(8f) | bl(8f)] = 64B contiguous,
// row i0+1 holds [tr | br]. Lane c = tid&3 loads 16B chunk c of each row
// segment -> 2 gather instructions per point-group (16 points/wave/instr),
// ~1.5 lines per 64B segment (32B-aligned) instead of 8 separate
// line-transactions per point. Lines/point: ~3.0 gather + 0.5 store + 0.13
// coords ~= 3.6 vs direct kernel's 8.7.
//
// Math (reference naming: tl=V[i0][i1], tr=V[i0+1][i1], bl=V[i0][i1+1],
// br=V[i0+1][i1+1]; mt = tr + d0*(tl-tr), mb = br + d0*(bl-br),
// out = mb + d1*(mt-mb)):
//   lane c<2:  rA = tl chunk, rB = tr chunk -> v = rB + d0*(rA-rB) = mt
//   lane c>=2: rA = bl chunk, rB = br chunk -> v = rB + d0*(rA-rB) = mb
//   shfl_xor(v, 2) swaps mt<->mb between partner lanes (same point, so
//   partners are always uniformly active, including tail waves);
//   lanes c<2 store out chunk c (32 active lanes, contiguous 512B/wave).
__global__ __launch_bounds__(256) void idx2pixel_coop(
    const float* __restrict__ coords,   // (N, 2)
    const float* __restrict__ visible,  // (H, W, C) row-major
    float* __restrict__ out,            // (N, C)
    int n)
{
    int tid = blockIdx.x * 256 + threadIdx.x;
    int point = tid >> 2;          // one point per 4-lane group
    int c = threadIdx.x & 3;       // chunk within the 64B row segment
    if (point >= n) return;        // partner lanes share `point`: uniform exit

    // 4 lanes read the same 8B -> merges to one line-transaction per 2 groups
    f32x2 co = reinterpret_cast<const f32x2*>(coords)[point];

    // c = (coord - 1) mod 2044 + 1 (floored mod, positive divisor)
    float cx = fmodf(co.x - 1.0f, MODV); if (cx < 0.0f) cx += MODV; cx += 1.0f;
    float cy = fmodf(co.y - 1.0f, MODV); if (cy < 0.0f) cy += MODV; cy += 1.0f;
    float fx = floorf(cx);
    float fy = floorf(cy);
    float d0 = cx - fx;            // delta along dim 0 (rows)
    float d1 = cy - fy;            // delta along dim 1 (cols)
    int i0 = (int)fx;              // row in [1, 2044]
    int i1 = (int)fy;              // col in [1, 2044] (i1+1 <= 2045 < 2048)
    // off = c > dims (unreachable since c < 2045; kept for fidelity)
    float m = (cx > (float)HH) ? 0.0f : 1.0f;

    const float* p = visible + ((size_t)i0 * WW + (size_t)i1) * CC + c * 4;
    f32x4 rA = *(const f32x4*)(p);                      // row i0:   [tl|bl] chunk c
    f32x4 rB = *(const f32x4*)(p + (size_t)WW * CC);    // row i0+1: [tr|br] chunk c

    // d0-lerp: mt on lanes c<2, mb on lanes c>=2 (same formula)
    f32x4 v = rB + d0 * (rA - rB);

    // partner (c^2) delivers the other mid for the same channels
    f32x4 w;
    w.x = __shfl_xor(v.x, 2, 64);
    w.y = __shfl_xor(v.y, 2, 64);
    w.z = __shfl_xor(v.z, 2, 64);
    w.w = __shfl_xor(v.w, 2, 64);

    if (c < 2) {
        // v = mt chunk, w = mb chunk; out = mb + d1*(mt - mb)
        f32x4 o = m * (w + d1 * (v - w));
        *(f32x4*)(out + (size_t)point * CC + c * 4) = o;
    }
}

extern "C" void kernel_launch(void* const* d_in, const int* in_sizes, int n_in,
                              void* d_out, int out_size, void* d_ws, size_t ws_size,
                              hipStream_t stream) {
    const float* coords  = (const float*)d_in[0];  // (N, 2) fp32
    const float* visible = (const float*)d_in[1];  // (2048, 2048, 8) fp32
    float* out = (float*)d_out;                    // (N, 8) fp32
    int n = in_sizes[0] / 2;

    // 4 threads per point, 64 points per 256-thread block
    int grid = (n + 63) / 64;
    idx2pixel_coop<<<grid, 256, 0, stream>>>(coords, visible, out, n);
}